// Round 1
// baseline (817.905 us; speedup 1.0000x reference)
//
#include <hip/hip_runtime.h>
#include <hip/hip_bf16.h>

// Problem constants (fixed by the reference)
#define IN_F   100
#define HID_F  128
#define OUT_F  47

// ---------------------------------------------------------------------------
// CSR build
// ---------------------------------------------------------------------------
__global__ void count_kernel(const int* __restrict__ row, int E, int* __restrict__ cnt) {
    int e = blockIdx.x * blockDim.x + threadIdx.x;
    if (e < E) atomicAdd(&cnt[row[e]], 1);
}

__global__ void dis_kernel(const int* __restrict__ cnt, float* __restrict__ dis, int N) {
    int i = blockIdx.x * blockDim.x + threadIdx.x;
    if (i < N) dis[i] = rsqrtf((float)cnt[i] + 1.0f);   // +1 for self loop
}

// single-block exclusive scan over N counts -> offs[0..N]
__global__ void scan_kernel(const int* __restrict__ cnt, int* __restrict__ offs, int N) {
    __shared__ int s[1024];
    int tid = threadIdx.x;
    int per = (N + 1023) >> 10;
    int start = min(tid * per, N);
    int end   = min(start + per, N);
    int sum = 0;
    for (int i = start; i < end; ++i) sum += cnt[i];
    s[tid] = sum;
    __syncthreads();
    // Hillis-Steele inclusive scan
    for (int off = 1; off < 1024; off <<= 1) {
        int v = (tid >= off) ? s[tid - off] : 0;
        __syncthreads();
        s[tid] += v;
        __syncthreads();
    }
    int run = (tid > 0) ? s[tid - 1] : 0;   // exclusive prefix of this chunk
    for (int i = start; i < end; ++i) { offs[i] = run; run += cnt[i]; }
    if (tid == 1023) offs[N] = run;         // last chunk is empty/ends at N -> run == total
}

__global__ void fill_kernel(const int* __restrict__ row, const int* __restrict__ col, int E,
                            const int* __restrict__ offs, int* __restrict__ fill,
                            const float* __restrict__ dis,
                            int* __restrict__ ccol, float* __restrict__ cw) {
    int e = blockIdx.x * blockDim.x + threadIdx.x;
    if (e < E) {
        int r = row[e], c = col[e];
        int pos = offs[r] + atomicAdd(&fill[r], 1);
        ccol[pos] = c;
        cw[pos]   = dis[r] * dis[c];
    }
}

// ---------------------------------------------------------------------------
// Aggregation: agg[i,:] = sum_e w_e * x[col_e,:]  +  2*dis[i]^2 * x[i,:]
// one wave per node; lane covers features [2*lane, 2*lane+1]
// ---------------------------------------------------------------------------
template <int F>
__global__ __launch_bounds__(256) void agg_kernel(
    const float* __restrict__ x, const int* __restrict__ offs,
    const int* __restrict__ ccol, const float* __restrict__ cw,
    const float* __restrict__ dis, float* __restrict__ agg, int N) {
    int gthread = blockIdx.x * blockDim.x + threadIdx.x;
    int node = gthread >> 6;
    int lane = threadIdx.x & 63;
    if (node >= N) return;
    constexpr int H = F / 2;      // 50 or 64 float2's per row
    if (lane >= H) return;
    const int f2 = lane * 2;
    float ax = 0.f, ay = 0.f;
    int s = offs[node], e = offs[node + 1];
    for (int p = s; p < e; ++p) {
        int   c = ccol[p];        // broadcast
        float w = cw[p];          // broadcast
        float2 v = *(const float2*)(x + (size_t)c * F + f2);
        ax += w * v.x;
        ay += w * v.y;
    }
    float d  = dis[node];
    float sw = 2.0f * d * d;      // self loop with diag enhancement (doubled)
    float2 v = *(const float2*)(x + (size_t)node * F + f2);
    ax += sw * v.x;
    ay += sw * v.y;
    float2 o; o.x = ax; o.y = ay;
    *(float2*)(agg + (size_t)node * F + f2) = o;
}

// ---------------------------------------------------------------------------
// Fused GEMM + LayerNorm (+ReLU):  out = LN( [agg, x] @ W )
// thread-per-node; acc[FOUT] in registers; W rows are wave-uniform -> s_load
// ---------------------------------------------------------------------------
template <int F, int FOUT, bool RELU>
__global__ __launch_bounds__(256) void gemm_ln_kernel(
    const float* __restrict__ A, const float* __restrict__ X,
    const float* __restrict__ W, float* __restrict__ out, int N) {
    int i = blockIdx.x * 256 + threadIdx.x;
    if (i >= N) return;

    float acc[FOUT];
#pragma unroll
    for (int j = 0; j < FOUT; ++j) acc[j] = 0.f;

    const float* arow = A + (size_t)i * F;
    const float* xrow = X + (size_t)i * F;

    // first half of W multiplies agg
#pragma unroll 1
    for (int k = 0; k < F; k += 4) {
        float4 v = *(const float4*)(arow + k);
        const float* wr = W + (size_t)k * FOUT;
#pragma unroll
        for (int j = 0; j < FOUT; ++j) acc[j] += v.x * wr[j];
        wr += FOUT;
#pragma unroll
        for (int j = 0; j < FOUT; ++j) acc[j] += v.y * wr[j];
        wr += FOUT;
#pragma unroll
        for (int j = 0; j < FOUT; ++j) acc[j] += v.z * wr[j];
        wr += FOUT;
#pragma unroll
        for (int j = 0; j < FOUT; ++j) acc[j] += v.w * wr[j];
    }
    // second half of W multiplies x
#pragma unroll 1
    for (int k = 0; k < F; k += 4) {
        float4 v = *(const float4*)(xrow + k);
        const float* wr = W + (size_t)(F + k) * FOUT;
#pragma unroll
        for (int j = 0; j < FOUT; ++j) acc[j] += v.x * wr[j];
        wr += FOUT;
#pragma unroll
        for (int j = 0; j < FOUT; ++j) acc[j] += v.y * wr[j];
        wr += FOUT;
#pragma unroll
        for (int j = 0; j < FOUT; ++j) acc[j] += v.z * wr[j];
        wr += FOUT;
#pragma unroll
        for (int j = 0; j < FOUT; ++j) acc[j] += v.w * wr[j];
    }

    // layer norm over the register row
    float mu = 0.f;
#pragma unroll
    for (int j = 0; j < FOUT; ++j) mu += acc[j];
    mu *= (1.0f / FOUT);
    float var = 0.f;
#pragma unroll
    for (int j = 0; j < FOUT; ++j) { float d = acc[j] - mu; var += d * d; }
    var *= (1.0f / FOUT);
    float inv = rsqrtf(var + 1e-5f);

    float* orow = out + (size_t)i * FOUT;
    if constexpr ((FOUT & 3) == 0) {
#pragma unroll
        for (int j = 0; j < FOUT; j += 4) {
            float4 o;
            o.x = (acc[j + 0] - mu) * inv;
            o.y = (acc[j + 1] - mu) * inv;
            o.z = (acc[j + 2] - mu) * inv;
            o.w = (acc[j + 3] - mu) * inv;
            if (RELU) {
                o.x = fmaxf(o.x, 0.f); o.y = fmaxf(o.y, 0.f);
                o.z = fmaxf(o.z, 0.f); o.w = fmaxf(o.w, 0.f);
            }
            *(float4*)(orow + j) = o;
        }
    } else {
#pragma unroll
        for (int j = 0; j < FOUT; ++j) {
            float v = (acc[j] - mu) * inv;
            if (RELU) v = fmaxf(v, 0.f);
            orow[j] = v;
        }
    }
}

// ---------------------------------------------------------------------------
extern "C" void kernel_launch(void* const* d_in, const int* in_sizes, int n_in,
                              void* d_out, int out_size, void* d_ws, size_t ws_size,
                              hipStream_t stream) {
    const float* x  = (const float*)d_in[0];
    const int*   ei = (const int*)d_in[1];
    const float* W1 = (const float*)d_in[2];
    const float* W2 = (const float*)d_in[3];
    const float* W3 = (const float*)d_in[4];
    float* out = (float*)d_out;

    const int N = in_sizes[0] / IN_F;   // 50000
    const int E = in_sizes[1] / 2;      // 800000
    const int* erow = ei;
    const int* ecol = ei + E;

    // workspace carve-out (256B aligned)
    char* p = (char*)d_ws;
    auto alloc = [&](size_t bytes) -> void* {
        void* r = (void*)p;
        p += (bytes + 255) & ~(size_t)255;
        return r;
    };
    int*   cnt  = (int*)  alloc((size_t)N * 4);
    int*   offs = (int*)  alloc((size_t)(N + 1) * 4);
    int*   fill = (int*)  alloc((size_t)N * 4);
    float* dis  = (float*)alloc((size_t)N * 4);
    int*   ccol = (int*)  alloc((size_t)E * 4);
    float* cw   = (float*)alloc((size_t)E * 4);
    float* agg  = (float*)alloc((size_t)N * HID_F * 4);
    float* h1   = (float*)alloc((size_t)N * HID_F * 4);
    float* h2   = (float*)alloc((size_t)N * HID_F * 4);

    hipMemsetAsync(cnt,  0, (size_t)N * 4, stream);
    hipMemsetAsync(fill, 0, (size_t)N * 4, stream);

    const int egrid = (E + 255) / 256;
    const int ngrid = (N + 255) / 256;

    count_kernel<<<egrid, 256, 0, stream>>>(erow, E, cnt);
    dis_kernel<<<ngrid, 256, 0, stream>>>(cnt, dis, N);
    scan_kernel<<<1, 1024, 0, stream>>>(cnt, offs, N);
    fill_kernel<<<egrid, 256, 0, stream>>>(erow, ecol, E, offs, fill, dis, ccol, cw);

    const int agrid = (N + 3) / 4;  // one wave (64 threads) per node, 256-thread blocks

    // layer 1: F=100 -> 128, relu
    agg_kernel<IN_F><<<agrid, 256, 0, stream>>>(x, offs, ccol, cw, dis, agg, N);
    gemm_ln_kernel<IN_F, HID_F, true><<<ngrid, 256, 0, stream>>>(agg, x, W1, h1, N);

    // layer 2: F=128 -> 128, relu
    agg_kernel<HID_F><<<agrid, 256, 0, stream>>>(h1, offs, ccol, cw, dis, agg, N);
    gemm_ln_kernel<HID_F, HID_F, true><<<ngrid, 256, 0, stream>>>(agg, h1, W2, h2, N);

    // layer 3: F=128 -> 47, no relu
    agg_kernel<HID_F><<<agrid, 256, 0, stream>>>(h2, offs, ccol, cw, dis, agg, N);
    gemm_ln_kernel<HID_F, OUT_F, false><<<ngrid, 256, 0, stream>>>(agg, h2, W3, out, N);
}

// Round 2
// 631.855 us; speedup vs baseline: 1.2944x; 1.2944x over previous
//
#include <hip/hip_runtime.h>

#define IN_F   100
#define HID_F  128
#define OUT_F  47
#define KP     256   // unified padded K / row stride for A and WT buffers

typedef short bf16x8 __attribute__((ext_vector_type(8)));
typedef float f32x4  __attribute__((ext_vector_type(4)));

__device__ __forceinline__ unsigned short f2bf(float f) {
    unsigned int u = __float_as_uint(f);
    u += 0x7FFFu + ((u >> 16) & 1u);           // round-to-nearest-even
    return (unsigned short)(u >> 16);
}
__device__ __forceinline__ float bf2f(unsigned short b) {
    return __uint_as_float(((unsigned int)b) << 16);
}

// ---------------------------------------------------------------------------
// CSR build
// ---------------------------------------------------------------------------
__global__ void count_kernel(const int* __restrict__ row, int E, int* __restrict__ cnt) {
    int e = blockIdx.x * blockDim.x + threadIdx.x;
    if (e < E) atomicAdd(&cnt[row[e]], 1);
}

__global__ void dis_kernel(const int* __restrict__ cnt, float* __restrict__ dis, int N) {
    int i = blockIdx.x * blockDim.x + threadIdx.x;
    if (i < N) dis[i] = rsqrtf((float)cnt[i] + 1.0f);   // +1 self loop
}

__global__ void scan_kernel(const int* __restrict__ cnt, int* __restrict__ offs, int N) {
    __shared__ int s[1024];
    int tid = threadIdx.x;
    int per = (N + 1023) >> 10;
    int start = min(tid * per, N);
    int end   = min(start + per, N);
    int sum = 0;
    for (int i = start; i < end; ++i) sum += cnt[i];
    s[tid] = sum;
    __syncthreads();
    for (int off = 1; off < 1024; off <<= 1) {
        int v = (tid >= off) ? s[tid - off] : 0;
        __syncthreads();
        s[tid] += v;
        __syncthreads();
    }
    int run = (tid > 0) ? s[tid - 1] : 0;
    for (int i = start; i < end; ++i) { offs[i] = run; run += cnt[i]; }
    if (tid == 1023) offs[N] = run;
}

__global__ void fill_kernel(const int* __restrict__ row, const int* __restrict__ col, int E,
                            const int* __restrict__ offs, int* __restrict__ fill,
                            const float* __restrict__ dis,
                            int* __restrict__ ccol, float* __restrict__ cw) {
    int e = blockIdx.x * blockDim.x + threadIdx.x;
    if (e < E) {
        int r = row[e], c = col[e];
        int pos = offs[r] + atomicAdd(&fill[r], 1);
        ccol[pos] = c;
        cw[pos]   = dis[r] * dis[c];
    }
}

// ---------------------------------------------------------------------------
// Prep: layer-1 x half into A buffer (cols [100,200) = x, [200,256) = 0,
// cols [96,100) zeroed here then overwritten by agg)
// ---------------------------------------------------------------------------
__global__ void xprep_kernel(const float* __restrict__ x,
                             unsigned short* __restrict__ Ahi,
                             unsigned short* __restrict__ Alo) {
    int node = blockIdx.x;
    int col  = 96 + threadIdx.x;          // block = 160 threads -> cols 96..255
    float v = 0.f;
    if (col >= 100 && col < 200) v = x[(size_t)node * IN_F + (col - 100)];
    unsigned short h = f2bf(v);
    unsigned short l = f2bf(v - bf2f(h));
    Ahi[(size_t)node * KP + col] = h;
    Alo[(size_t)node * KP + col] = l;
}

// W [KSRC][NSRC] -> WT hi/lo [NPAD][KP], zero padded
template <int KSRC, int NSRC>
__global__ void wtprep_kernel(const float* __restrict__ W,
                              unsigned short* __restrict__ hi,
                              unsigned short* __restrict__ lo) {
    int n = blockIdx.x;   // 0..NPAD-1
    for (int k = threadIdx.x; k < KP; k += blockDim.x) {
        float v = (k < KSRC && n < NSRC) ? W[(size_t)k * NSRC + n] : 0.f;
        unsigned short h = f2bf(v);
        hi[(size_t)n * KP + k] = h;
        lo[(size_t)n * KP + k] = f2bf(v - bf2f(h));
    }
}

// ---------------------------------------------------------------------------
// Aggregation -> bf16 hi/lo into A buffer cols [0,F)
// one wave per node; lane covers features [2*lane, 2*lane+1]
// ---------------------------------------------------------------------------
template <int F>
__global__ __launch_bounds__(256) void agg_kernel(
    const float* __restrict__ x, const int* __restrict__ offs,
    const int* __restrict__ ccol, const float* __restrict__ cw,
    const float* __restrict__ dis,
    unsigned short* __restrict__ Ahi, unsigned short* __restrict__ Alo, int N) {
    int gthread = blockIdx.x * blockDim.x + threadIdx.x;
    int node = gthread >> 6;
    int lane = threadIdx.x & 63;
    if (node >= N) return;
    constexpr int H = F / 2;
    if (lane >= H) return;
    const int f2 = lane * 2;
    float ax = 0.f, ay = 0.f;
    int s = offs[node], e = offs[node + 1];
    for (int p = s; p < e; ++p) {
        int   c = ccol[p];
        float w = cw[p];
        float2 v = *(const float2*)(x + (size_t)c * F + f2);
        ax += w * v.x;
        ay += w * v.y;
    }
    float d  = dis[node];
    float sw = 2.0f * d * d;
    float2 v = *(const float2*)(x + (size_t)node * F + f2);
    ax += sw * v.x;
    ay += sw * v.y;

    unsigned short hx = f2bf(ax), hy = f2bf(ay);
    unsigned short lx = f2bf(ax - bf2f(hx)), ly = f2bf(ay - bf2f(hy));
    *(unsigned int*)(Ahi + (size_t)node * KP + f2) = (unsigned int)hx | ((unsigned int)hy << 16);
    *(unsigned int*)(Alo + (size_t)node * KP + f2) = (unsigned int)lx | ((unsigned int)ly << 16);
}

// ---------------------------------------------------------------------------
// MFMA GEMM (split bf16: ah*bh + al*bh + ah*bl) + fused LayerNorm (+ReLU)
// one wave per 16-node tile; NT 16-col tiles; K = KP = 256
// C/D layout: col = lane&15, row = (lane>>4)*4 + reg   [HW-verified]
// ---------------------------------------------------------------------------
template <int NT, int NOUT, bool RELU, bool WNEXT>
__global__ __launch_bounds__(256) void mfma_gemm_ln(
    const unsigned short* __restrict__ Ahi, const unsigned short* __restrict__ Alo,
    const unsigned short* __restrict__ WThi, const unsigned short* __restrict__ WTlo,
    float* __restrict__ hout,
    unsigned short* __restrict__ AnHi, unsigned short* __restrict__ AnLo,
    int ntiles) {
    int wave = blockIdx.x * 4 + (threadIdx.x >> 6);
    if (wave >= ntiles) return;
    int lane = threadIdx.x & 63;
    int c16  = lane & 15;          // A row within tile / B col / C col
    int koff = (lane >> 4) * 8;    // k sub-offset

    const unsigned short* pah = Ahi + (size_t)(wave * 16 + c16) * KP + koff;
    const unsigned short* pal = Alo + (size_t)(wave * 16 + c16) * KP + koff;
    const unsigned short* pbh = WThi + (size_t)c16 * KP + koff;
    const unsigned short* pbl = WTlo + (size_t)c16 * KP + koff;

    f32x4 acc[NT];
#pragma unroll
    for (int t = 0; t < NT; ++t) acc[t] = (f32x4){0.f, 0.f, 0.f, 0.f};

#pragma unroll 2
    for (int kk = 0; kk < KP; kk += 32) {
        bf16x8 ah = *(const bf16x8*)(pah + kk);
        bf16x8 al = *(const bf16x8*)(pal + kk);
#pragma unroll
        for (int t = 0; t < NT; ++t) {
            bf16x8 bh = *(const bf16x8*)(pbh + (size_t)t * 16 * KP + kk);
            bf16x8 bl = *(const bf16x8*)(pbl + (size_t)t * 16 * KP + kk);
            acc[t] = __builtin_amdgcn_mfma_f32_16x16x32_bf16(ah, bh, acc[t], 0, 0, 0);
            acc[t] = __builtin_amdgcn_mfma_f32_16x16x32_bf16(al, bh, acc[t], 0, 0, 0);
            acc[t] = __builtin_amdgcn_mfma_f32_16x16x32_bf16(ah, bl, acc[t], 0, 0, 0);
        }
    }

    // fused LayerNorm: stats per row via 16-lane (col-group) reductions
    int g = lane >> 4;
    float mu[4], inv[4];
#pragma unroll
    for (int r = 0; r < 4; ++r) {
        float s = 0.f, q = 0.f;
#pragma unroll
        for (int t = 0; t < NT; ++t) {
            float v = acc[t][r];
            bool valid = (NT * 16 == NOUT) || (t * 16 + c16 < NOUT);
            if (valid) { s += v; q += v * v; }
        }
#pragma unroll
        for (int m = 8; m >= 1; m >>= 1) {
            s += __shfl_xor(s, m, 64);
            q += __shfl_xor(q, m, 64);
        }
        float mean = s * (1.0f / NOUT);
        float var  = q * (1.0f / NOUT) - mean * mean;
        mu[r]  = mean;
        inv[r] = rsqrtf(var + 1e-5f);
    }

    int mbase = wave * 16 + g * 4;
#pragma unroll
    for (int r = 0; r < 4; ++r) {
        int m = mbase + r;
        float* orow = hout + (size_t)m * NOUT;
#pragma unroll
        for (int t = 0; t < NT; ++t) {
            int col = t * 16 + c16;
            if (NT * 16 != NOUT && col >= NOUT) continue;
            float v = (acc[t][r] - mu[r]) * inv[r];
            if (RELU) v = fmaxf(v, 0.f);
            orow[col] = v;
            if (WNEXT) {   // next layer's x-half at cols [128,256)
                unsigned short h = f2bf(v);
                AnHi[(size_t)m * KP + 128 + col] = h;
                AnLo[(size_t)m * KP + 128 + col] = f2bf(v - bf2f(h));
            }
        }
    }
}

// ---------------------------------------------------------------------------
extern "C" void kernel_launch(void* const* d_in, const int* in_sizes, int n_in,
                              void* d_out, int out_size, void* d_ws, size_t ws_size,
                              hipStream_t stream) {
    const float* x  = (const float*)d_in[0];
    const int*   ei = (const int*)d_in[1];
    const float* W1 = (const float*)d_in[2];
    const float* W2 = (const float*)d_in[3];
    const float* W3 = (const float*)d_in[4];
    float* out = (float*)d_out;

    const int N = in_sizes[0] / IN_F;   // 50000
    const int E = in_sizes[1] / 2;      // 800000
    const int* erow = ei;
    const int* ecol = ei + E;

    char* p = (char*)d_ws;
    auto alloc = [&](size_t bytes) -> void* {
        void* r = (void*)p;
        p += (bytes + 255) & ~(size_t)255;
        return r;
    };
    int*   cnt  = (int*)  alloc((size_t)N * 4);
    int*   offs = (int*)  alloc((size_t)(N + 1) * 4);
    int*   fill = (int*)  alloc((size_t)N * 4);
    float* dis  = (float*)alloc((size_t)N * 4);
    int*   ccol = (int*)  alloc((size_t)E * 4);
    float* cw   = (float*)alloc((size_t)E * 4);
    unsigned short* ABhi = (unsigned short*)alloc((size_t)N * KP * 2);   // shared A for L1/L2/L3
    unsigned short* ABlo = (unsigned short*)alloc((size_t)N * KP * 2);
    float* h = (float*)alloc((size_t)N * HID_F * 4);                     // h1 then h2
    unsigned short* WT1h = (unsigned short*)alloc((size_t)HID_F * KP * 2);
    unsigned short* WT1l = (unsigned short*)alloc((size_t)HID_F * KP * 2);
    unsigned short* WT2h = (unsigned short*)alloc((size_t)HID_F * KP * 2);
    unsigned short* WT2l = (unsigned short*)alloc((size_t)HID_F * KP * 2);
    unsigned short* WT3h = (unsigned short*)alloc((size_t)48 * KP * 2);
    unsigned short* WT3l = (unsigned short*)alloc((size_t)48 * KP * 2);

    hipMemsetAsync(cnt,  0, (size_t)N * 4, stream);
    hipMemsetAsync(fill, 0, (size_t)N * 4, stream);

    const int egrid = (E + 255) / 256;
    const int ngrid = (N + 255) / 256;

    count_kernel<<<egrid, 256, 0, stream>>>(erow, E, cnt);
    dis_kernel<<<ngrid, 256, 0, stream>>>(cnt, dis, N);
    scan_kernel<<<1, 1024, 0, stream>>>(cnt, offs, N);
    fill_kernel<<<egrid, 256, 0, stream>>>(erow, ecol, E, offs, fill, dis, ccol, cw);

    // weight transposes + layer-1 x half (independent of CSR; cheap)
    wtprep_kernel<2 * IN_F,  HID_F><<<HID_F, 256, 0, stream>>>(W1, WT1h, WT1l);
    wtprep_kernel<2 * HID_F, HID_F><<<HID_F, 256, 0, stream>>>(W2, WT2h, WT2l);
    wtprep_kernel<2 * HID_F, OUT_F><<<48,    256, 0, stream>>>(W3, WT3h, WT3l);
    xprep_kernel<<<N, 160, 0, stream>>>(x, ABhi, ABlo);

    const int agrid  = (N + 3) / 4;            // wave per node
    const int ntiles = N / 16;                 // 3125 exactly
    const int ggrid  = (ntiles + 3) / 4;       // 4 waves per block

    // layer 1
    agg_kernel<IN_F><<<agrid, 256, 0, stream>>>(x, offs, ccol, cw, dis, ABhi, ABlo, N);
    mfma_gemm_ln<8, HID_F, true, true><<<ggrid, 256, 0, stream>>>(
        ABhi, ABlo, WT1h, WT1l, h, ABhi, ABlo, ntiles);

    // layer 2
    agg_kernel<HID_F><<<agrid, 256, 0, stream>>>(h, offs, ccol, cw, dis, ABhi, ABlo, N);
    mfma_gemm_ln<8, HID_F, true, true><<<ggrid, 256, 0, stream>>>(
        ABhi, ABlo, WT2h, WT2l, h, ABhi, ABlo, ntiles);

    // layer 3
    agg_kernel<HID_F><<<agrid, 256, 0, stream>>>(h, offs, ccol, cw, dis, ABhi, ABlo, N);
    mfma_gemm_ln<3, OUT_F, false, false><<<ggrid, 256, 0, stream>>>(
        ABhi, ABlo, WT3h, WT3l, out, nullptr, nullptr, ntiles);
}

// Round 3
// 445.489 us; speedup vs baseline: 1.8360x; 1.4183x over previous
//
#include <hip/hip_runtime.h>

#define IN_F   100
#define HID_F  128
#define OUT_F  47

typedef short bf16x8 __attribute__((ext_vector_type(8)));
typedef float f32x4  __attribute__((ext_vector_type(4)));
typedef unsigned short u16;
typedef unsigned int   u32;

__device__ __forceinline__ u16 f2bf(float f) {
    u32 u = __float_as_uint(f);
    u += 0x7FFFu + ((u >> 16) & 1u);           // RNE
    return (u16)(u >> 16);
}
__device__ __forceinline__ float bf2f(u16 b) { return __uint_as_float(((u32)b) << 16); }
__device__ __forceinline__ float lo2f(u32 v) { return __uint_as_float(v << 16); }
__device__ __forceinline__ float hi2f(u32 v) { return __uint_as_float(v & 0xFFFF0000u); }

// ---------------------------------------------------------------------------
// CSR build
// ---------------------------------------------------------------------------
__global__ void count_kernel(const int* __restrict__ row, int E, int* __restrict__ cnt) {
    int e = blockIdx.x * blockDim.x + threadIdx.x;
    if (e < E) atomicAdd(&cnt[row[e]], 1);
}

__global__ void dis_kernel(const int* __restrict__ cnt, float* __restrict__ dis, int N) {
    int i = blockIdx.x * blockDim.x + threadIdx.x;
    if (i < N) dis[i] = rsqrtf((float)cnt[i] + 1.0f);   // +1 self loop
}

__global__ void scan_kernel(const int* __restrict__ cnt, int* __restrict__ offs, int N) {
    __shared__ int s[1024];
    int tid = threadIdx.x;
    int per = (N + 1023) >> 10;
    int start = min(tid * per, N);
    int end   = min(start + per, N);
    int sum = 0;
    for (int i = start; i < end; ++i) sum += cnt[i];
    s[tid] = sum;
    __syncthreads();
    for (int off = 1; off < 1024; off <<= 1) {
        int v = (tid >= off) ? s[tid - off] : 0;
        __syncthreads();
        s[tid] += v;
        __syncthreads();
    }
    int run = (tid > 0) ? s[tid - 1] : 0;
    for (int i = start; i < end; ++i) { offs[i] = run; run += cnt[i]; }
    if (tid == 1023) offs[N] = run;
}

__global__ void fill_kernel(const int* __restrict__ row, const int* __restrict__ col, int E,
                            const int* __restrict__ offs, int* __restrict__ fill,
                            const float* __restrict__ dis,
                            int* __restrict__ ccol, float* __restrict__ cw) {
    int e = blockIdx.x * blockDim.x + threadIdx.x;
    if (e < E) {
        int r = row[e], c = col[e];
        int pos = offs[r] + atomicAdd(&fill[r], 1);
        ccol[pos] = c;
        cw[pos]   = dis[r] * dis[c];
    }
}

// ---------------------------------------------------------------------------
// A1 = x padded to [N][128], split hi/lo bf16
// ---------------------------------------------------------------------------
__global__ void xprep_kernel(const float* __restrict__ x,
                             u16* __restrict__ Ahi, u16* __restrict__ Alo, int N) {
    int idx = blockIdx.x * 256 + threadIdx.x;
    if (idx >= N * 128) return;
    int node = idx >> 7, col = idx & 127;
    float v = (col < IN_F) ? x[(size_t)node * IN_F + col] : 0.f;
    u16 h = f2bf(v);
    Ahi[idx] = h;
    Alo[idx] = f2bf(v - bf2f(h));
}

// B = [ Wa^T ; Wx^T ] as [2*NPAD][128] hi/lo.  W is [2*KSRC][NSRC].
template <int KSRC, int NSRC, int NPAD>
__global__ void wtprep_kernel(const float* __restrict__ W,
                              u16* __restrict__ Bh, u16* __restrict__ Bl) {
    int n = blockIdx.x;                 // 0 .. 2*NPAD-1
    int half = (n >= NPAD) ? 1 : 0;
    int cc = n - half * NPAD;
    int k = threadIdx.x;                // 0..127
    float v = (cc < NSRC && k < KSRC) ? W[(size_t)(half * KSRC + k) * NSRC + cc] : 0.f;
    u16 h = f2bf(v);
    Bh[(size_t)n * 128 + k] = h;
    Bl[(size_t)n * 128 + k] = f2bf(v - bf2f(h));
}

// ---------------------------------------------------------------------------
// GEMM: [y | z] = A @ B^T.  A [N][128] hi/lo bf16 (LDS-staged per 16-row tile),
// B [H/8*16][128] hi/lo.  y -> bf16 [N][H], z -> f32 [N][H].
// 4 waves/block, wave w handles output tiles {w, w+4, ...}.
// C/D frag: col = lane&15, row = (lane>>4)*4 + reg.
// ---------------------------------------------------------------------------
template <int H>   // 128 or 48
__global__ __launch_bounds__(256) void mfma_gemm(
    const u16* __restrict__ Ahi, const u16* __restrict__ Alo,
    const u16* __restrict__ Bh, const u16* __restrict__ Bl,
    u16* __restrict__ y, float* __restrict__ z, int N) {
    constexpr int NTOT = H / 8;          // 16-col output tiles (16 or 6)
    __shared__ u16 sA[2][16 * 136];      // padded stride 136 halfwords (272B)
    int tid = threadIdx.x;
    int m0 = blockIdx.x * 16;

    {   // stage A tile: 256 threads x 16B each for hi and lo
        int row = tid >> 4, seg = tid & 15;
        *(bf16x8*)(&sA[0][row * 136 + seg * 8]) =
            *(const bf16x8*)(Ahi + (size_t)(m0 + row) * 128 + seg * 8);
        *(bf16x8*)(&sA[1][row * 136 + seg * 8]) =
            *(const bf16x8*)(Alo + (size_t)(m0 + row) * 128 + seg * 8);
    }
    __syncthreads();

    int w    = tid >> 6;
    int lane = tid & 63;
    int c16  = lane & 15;
    int g    = lane >> 4;
    int koff = g * 8;

    f32x4 acc[4];
#pragma unroll
    for (int i = 0; i < 4; ++i) acc[i] = (f32x4){0.f, 0.f, 0.f, 0.f};

#pragma unroll
    for (int kk = 0; kk < 128; kk += 32) {
        bf16x8 ah = *(const bf16x8*)(&sA[0][c16 * 136 + koff + kk]);
        bf16x8 al = *(const bf16x8*)(&sA[1][c16 * 136 + koff + kk]);
#pragma unroll
        for (int i = 0; i < 4; ++i) {
            int t = w + i * 4;
            if (t < NTOT) {
                bf16x8 bh = *(const bf16x8*)(Bh + (size_t)(t * 16 + c16) * 128 + koff + kk);
                bf16x8 bl = *(const bf16x8*)(Bl + (size_t)(t * 16 + c16) * 128 + koff + kk);
                acc[i] = __builtin_amdgcn_mfma_f32_16x16x32_bf16(ah, bh, acc[i], 0, 0, 0);
                acc[i] = __builtin_amdgcn_mfma_f32_16x16x32_bf16(al, bh, acc[i], 0, 0, 0);
                acc[i] = __builtin_amdgcn_mfma_f32_16x16x32_bf16(ah, bl, acc[i], 0, 0, 0);
            }
        }
    }

#pragma unroll
    for (int i = 0; i < 4; ++i) {
        int t = w + i * 4;
        if (t < NTOT) {
            if (t < NTOT / 2) {          // y half -> bf16
                int col = t * 16 + c16;
#pragma unroll
                for (int r = 0; r < 4; ++r) {
                    int m = m0 + g * 4 + r;
                    y[(size_t)m * H + col] = f2bf(acc[i][r]);
                }
            } else {                     // z half -> f32
                int col = (t - NTOT / 2) * 16 + c16;
#pragma unroll
                for (int r = 0; r < 4; ++r) {
                    int m = m0 + g * 4 + r;
                    z[(size_t)m * H + col] = acc[i][r];
                }
            }
        }
    }
}

// ---------------------------------------------------------------------------
// Fused aggregation + LayerNorm (+ReLU / +hi-lo split for next layer's A).
// out_pre[i] = sum_e w_e * y[col_e] + 2*dis_i^2 * y[i] + z[i]
// wave per node; lane holds 2 cols (one dword of the bf16 y row).
// ---------------------------------------------------------------------------
template <int H, int HREAL, bool LAST>
__global__ __launch_bounds__(256) void agg_ln_kernel(
    const u16* __restrict__ y, const float* __restrict__ z,
    const int* __restrict__ offs, const int* __restrict__ ccol,
    const float* __restrict__ cw, const float* __restrict__ dis,
    u16* __restrict__ Hhi, u16* __restrict__ Hlo,
    float* __restrict__ out, int N) {
    int node = (blockIdx.x * 256 + threadIdx.x) >> 6;
    int lane = threadIdx.x & 63;
    if (node >= N) return;
    constexpr int ND = H / 2;                  // dwords per y row
    const bool act = lane < ND;
    const int col0 = lane * 2;
    const u32* yd = (const u32*)y;

    float a0 = 0.f, a1 = 0.f;
    if (act) {
        a0 = z[(size_t)node * H + col0];
        a1 = z[(size_t)node * H + col0 + 1];
    }
    {   // self loop (diag-enhanced): weight 2*dis^2
        float d = dis[node];
        float sw = 2.f * d * d;
        u32 v = act ? yd[(size_t)node * ND + lane] : 0u;
        a0 += sw * lo2f(v);
        a1 += sw * hi2f(v);
    }

    int s = offs[node], e = offs[node + 1];
    int p = s;
    int nUn = (e - s) & ~3;
    for (int q = 0; q < nUn; q += 4) {         // 4-deep MLP
        int c0 = ccol[p], c1 = ccol[p + 1], c2 = ccol[p + 2], c3 = ccol[p + 3];
        float w0 = cw[p], w1 = cw[p + 1], w2 = cw[p + 2], w3 = cw[p + 3];
        u32 v0 = 0u, v1 = 0u, v2 = 0u, v3 = 0u;
        if (act) {
            v0 = yd[(size_t)c0 * ND + lane];
            v1 = yd[(size_t)c1 * ND + lane];
            v2 = yd[(size_t)c2 * ND + lane];
            v3 = yd[(size_t)c3 * ND + lane];
        }
        a0 += w0 * lo2f(v0) + w1 * lo2f(v1) + w2 * lo2f(v2) + w3 * lo2f(v3);
        a1 += w0 * hi2f(v0) + w1 * hi2f(v1) + w2 * hi2f(v2) + w3 * hi2f(v3);
        p += 4;
    }
    for (; p < e; ++p) {
        int c = ccol[p];
        float w = cw[p];
        u32 v = act ? yd[(size_t)c * ND + lane] : 0u;
        a0 += w * lo2f(v);
        a1 += w * hi2f(v);
    }

    // LayerNorm stats over HREAL cols
    float s1 = 0.f, s2 = 0.f;
    if (act) {
        bool ok1 = (col0 + 1 < HREAL);
        s1 = a0 + (ok1 ? a1 : 0.f);
        s2 = a0 * a0 + (ok1 ? a1 * a1 : 0.f);
    }
#pragma unroll
    for (int m = 32; m >= 1; m >>= 1) {
        s1 += __shfl_xor(s1, m, 64);
        s2 += __shfl_xor(s2, m, 64);
    }
    float mu  = s1 * (1.0f / HREAL);
    float var = s2 * (1.0f / HREAL) - mu * mu;
    float inv = rsqrtf(var + 1e-5f);

    if (act) {
        if (LAST) {
            out[(size_t)node * HREAL + col0] = (a0 - mu) * inv;
            if (col0 + 1 < HREAL)
                out[(size_t)node * HREAL + col0 + 1] = (a1 - mu) * inv;
        } else {
            float o0 = fmaxf((a0 - mu) * inv, 0.f);
            float o1 = fmaxf((a1 - mu) * inv, 0.f);
            u16 h0 = f2bf(o0), h1 = f2bf(o1);
            u16 l0 = f2bf(o0 - bf2f(h0)), l1 = f2bf(o1 - bf2f(h1));
            ((u32*)Hhi)[(size_t)node * ND + lane] = (u32)h0 | ((u32)h1 << 16);
            ((u32*)Hlo)[(size_t)node * ND + lane] = (u32)l0 | ((u32)l1 << 16);
        }
    }
}

// ---------------------------------------------------------------------------
extern "C" void kernel_launch(void* const* d_in, const int* in_sizes, int n_in,
                              void* d_out, int out_size, void* d_ws, size_t ws_size,
                              hipStream_t stream) {
    const float* x  = (const float*)d_in[0];
    const int*   ei = (const int*)d_in[1];
    const float* W1 = (const float*)d_in[2];
    const float* W2 = (const float*)d_in[3];
    const float* W3 = (const float*)d_in[4];
    float* out = (float*)d_out;

    const int N = in_sizes[0] / IN_F;   // 50000
    const int E = in_sizes[1] / 2;      // 800000
    const int* erow = ei;
    const int* ecol = ei + E;

    char* p = (char*)d_ws;
    auto alloc = [&](size_t bytes) -> void* {
        void* r = (void*)p;
        p += (bytes + 255) & ~(size_t)255;
        return r;
    };
    int*   cnt  = (int*)  alloc((size_t)N * 4);
    int*   offs = (int*)  alloc((size_t)(N + 1) * 4);
    int*   fill = (int*)  alloc((size_t)N * 4);
    float* dis  = (float*)alloc((size_t)N * 4);
    int*   ccol = (int*)  alloc((size_t)E * 4);
    float* cw   = (float*)alloc((size_t)E * 4);
    u16*   Ahi  = (u16*)  alloc((size_t)N * 128 * 2);
    u16*   Alo  = (u16*)  alloc((size_t)N * 128 * 2);
    u16*   yb   = (u16*)  alloc((size_t)N * 128 * 2);
    float* zb   = (float*)alloc((size_t)N * 128 * 4);
    u16*   B1h  = (u16*)  alloc((size_t)256 * 128 * 2);
    u16*   B1l  = (u16*)  alloc((size_t)256 * 128 * 2);
    u16*   B2h  = (u16*)  alloc((size_t)256 * 128 * 2);
    u16*   B2l  = (u16*)  alloc((size_t)256 * 128 * 2);
    u16*   B3h  = (u16*)  alloc((size_t)96 * 128 * 2);
    u16*   B3l  = (u16*)  alloc((size_t)96 * 128 * 2);

    hipMemsetAsync(cnt,  0, (size_t)N * 4, stream);
    hipMemsetAsync(fill, 0, (size_t)N * 4, stream);

    const int egrid = (E + 255) / 256;
    const int ngrid = (N + 255) / 256;

    count_kernel<<<egrid, 256, 0, stream>>>(erow, E, cnt);
    dis_kernel<<<ngrid, 256, 0, stream>>>(cnt, dis, N);
    scan_kernel<<<1, 1024, 0, stream>>>(cnt, offs, N);
    fill_kernel<<<egrid, 256, 0, stream>>>(erow, ecol, E, offs, fill, dis, ccol, cw);

    wtprep_kernel<IN_F,  HID_F, 128><<<256, 128, 0, stream>>>(W1, B1h, B1l);
    wtprep_kernel<HID_F, HID_F, 128><<<256, 128, 0, stream>>>(W2, B2h, B2l);
    wtprep_kernel<HID_F, OUT_F, 48><<<96,  128, 0, stream>>>(W3, B3h, B3l);
    xprep_kernel<<<(N * 128 + 255) / 256, 256, 0, stream>>>(x, Ahi, Alo, N);

    const int gblocks = N / 16;          // 3125
    const int ablocks = (N + 3) / 4;     // wave per node

    // layer 1
    mfma_gemm<128><<<gblocks, 256, 0, stream>>>(Ahi, Alo, B1h, B1l, yb, zb, N);
    agg_ln_kernel<128, 128, false><<<ablocks, 256, 0, stream>>>(
        yb, zb, offs, ccol, cw, dis, Ahi, Alo, nullptr, N);

    // layer 2
    mfma_gemm<128><<<gblocks, 256, 0, stream>>>(Ahi, Alo, B2h, B2l, yb, zb, N);
    agg_ln_kernel<128, 128, false><<<ablocks, 256, 0, stream>>>(
        yb, zb, offs, ccol, cw, dis, Ahi, Alo, nullptr, N);

    // layer 3
    mfma_gemm<48><<<gblocks, 256, 0, stream>>>(Ahi, Alo, B3h, B3l, yb, zb, N);
    agg_ln_kernel<48, 47, true><<<ablocks, 256, 0, stream>>>(
        yb, zb, offs, ccol, cw, dis, nullptr, nullptr, out, N);
}

// Round 4
// 329.801 us; speedup vs baseline: 2.4800x; 1.3508x over previous
//
#include <hip/hip_runtime.h>

#define IN_F   100
#define HID_F  128
#define OUT_F  47

typedef short bf16x8 __attribute__((ext_vector_type(8)));
typedef float f32x4  __attribute__((ext_vector_type(4)));
typedef unsigned short u16;
typedef unsigned int   u32;

__device__ __forceinline__ u16 f2bf(float f) {
    u32 u = __float_as_uint(f);
    u += 0x7FFFu + ((u >> 16) & 1u);           // RNE
    return (u16)(u >> 16);
}
__device__ __forceinline__ float bf2f(u16 b) { return __uint_as_float(((u32)b) << 16); }
__device__ __forceinline__ float lo2f(u32 v) { return __uint_as_float(v << 16); }
__device__ __forceinline__ float hi2f(u32 v) { return __uint_as_float(v & 0xFFFF0000u); }

// ---------------------------------------------------------------------------
// CSR build
// ---------------------------------------------------------------------------
__global__ void count_kernel(const int* __restrict__ row, int E, int* __restrict__ cnt) {
    int e = blockIdx.x * blockDim.x + threadIdx.x;
    if (e < E) atomicAdd(&cnt[row[e]], 1);
}

// phase 1: per-256-block sums
__global__ void scan_bsum_kernel(const int* __restrict__ cnt, int* __restrict__ bsum, int N) {
    __shared__ int red[4];
    int i = blockIdx.x * 256 + threadIdx.x;
    int v = (i < N) ? cnt[i] : 0;
#pragma unroll
    for (int m = 32; m >= 1; m >>= 1) v += __shfl_xor(v, m, 64);
    if ((threadIdx.x & 63) == 0) red[threadIdx.x >> 6] = v;
    __syncthreads();
    if (threadIdx.x == 0) bsum[blockIdx.x] = red[0] + red[1] + red[2] + red[3];
}

// phase 2: exclusive scan of <=256 block sums (single block)
__global__ void scan_mid_kernel(int* __restrict__ bsum, int nb) {
    __shared__ int s[256];
    int t = threadIdx.x;
    int v = (t < nb) ? bsum[t] : 0;
    s[t] = v;
    __syncthreads();
    for (int o = 1; o < 256; o <<= 1) {
        int u = (t >= o) ? s[t - o] : 0;
        __syncthreads();
        s[t] += u;
        __syncthreads();
    }
    if (t < nb) bsum[t] = s[t] - v;     // exclusive
}

// phase 3: per-block exclusive scan + add block prefix; fuse dis = rsqrt(deg+1)
__global__ void scan_offs_kernel(const int* __restrict__ cnt, const int* __restrict__ bsum,
                                 int* __restrict__ offs, float* __restrict__ dis, int N, int E) {
    __shared__ int s[256];
    int b = blockIdx.x, t = threadIdx.x;
    int i = b * 256 + t;
    int v = (i < N) ? cnt[i] : 0;
    s[t] = v;
    __syncthreads();
    for (int o = 1; o < 256; o <<= 1) {
        int u = (t >= o) ? s[t - o] : 0;
        __syncthreads();
        s[t] += u;
        __syncthreads();
    }
    if (i < N) {
        offs[i] = bsum[b] + s[t] - v;
        dis[i]  = rsqrtf((float)v + 1.0f);   // +1 self loop
    }
    if (b == 0 && t == 0) offs[N] = E;
}

__global__ void fill_kernel(const int* __restrict__ row, const int* __restrict__ col, int E,
                            const int* __restrict__ offs, int* __restrict__ fill,
                            const float* __restrict__ dis,
                            int* __restrict__ ccol, float* __restrict__ cw) {
    int e = blockIdx.x * blockDim.x + threadIdx.x;
    if (e < E) {
        int r = row[e], c = col[e];
        int pos = offs[r] + atomicAdd(&fill[r], 1);
        ccol[pos] = c;
        cw[pos]   = dis[r] * dis[c];
    }
}

// ---------------------------------------------------------------------------
// All three weight preps in one launch.
// B_l = [ Wa^T ; Wx^T ] as [2*NPAD][128] hi/lo.
// ---------------------------------------------------------------------------
__global__ void wtprep_all_kernel(const float* __restrict__ W1, const float* __restrict__ W2,
                                  const float* __restrict__ W3,
                                  u16* __restrict__ B1h, u16* __restrict__ B1l,
                                  u16* __restrict__ B2h, u16* __restrict__ B2l,
                                  u16* __restrict__ B3h, u16* __restrict__ B3l) {
    int b = blockIdx.x, k = threadIdx.x;   // k: 0..127
    const float* W; u16 *Bh, *Bl; int KSRC, NSRC, NPAD, n;
    if (b < 256)      { W = W1; Bh = B1h; Bl = B1l; KSRC = IN_F;  NSRC = HID_F; NPAD = 128; n = b; }
    else if (b < 512) { W = W2; Bh = B2h; Bl = B2l; KSRC = HID_F; NSRC = HID_F; NPAD = 128; n = b - 256; }
    else              { W = W3; Bh = B3h; Bl = B3l; KSRC = HID_F; NSRC = OUT_F; NPAD = 48;  n = b - 512; }
    int half = (n >= NPAD) ? 1 : 0;
    int cc = n - half * NPAD;
    float v = (cc < NSRC && k < KSRC) ? W[(size_t)(half * KSRC + k) * NSRC + cc] : 0.f;
    u16 h = f2bf(v);
    Bh[(size_t)n * 128 + k] = h;
    Bl[(size_t)n * 128 + k] = f2bf(v - bf2f(h));
}

// ---------------------------------------------------------------------------
// Fused kernel: per 16-node tile —
//   phase 1 (FIRST):  stage x rows -> hi/lo bf16 in LDS (layer-1 input)
//   phase 1 (!FIRST): wave w gathers node m0+w over y/z (HIN=128), LN+ReLU,
//                     writes normalized hi/lo row into LDS
//   phase 2: wave w computes output tile w: [y|z] = A @ B^T (split-bf16 MFMA)
// HOUT: 128 or 48. y -> bf16 [N][HOUT], z -> f32 [N][HOUT].
// C/D frag: col = lane&15, row = (lane>>4)*4 + reg.
// ---------------------------------------------------------------------------
template <int HOUT, bool FIRST>
__global__ __launch_bounds__(1024) void fused_kernel(
    const float* __restrict__ x,
    const u16* __restrict__ yin, const float* __restrict__ zin,
    const int* __restrict__ offs, const int* __restrict__ ccol,
    const float* __restrict__ cw, const float* __restrict__ dis,
    const u16* __restrict__ Bh, const u16* __restrict__ Bl,
    u16* __restrict__ yout, float* __restrict__ zout, int N) {
    __shared__ u16 sA[2][16 * 136];     // padded stride 136 u16 (272 B)
    int tid = threadIdx.x;
    int m0 = blockIdx.x * 16;
    int w = tid >> 6, lane = tid & 63;

    if (FIRST) {
        // convert 16 rows of x (100 f32 -> 128 bf16 hi/lo)
#pragma unroll
        for (int idx = tid; idx < 16 * 128; idx += 1024) {
            int r = idx >> 7, c = idx & 127;
            float v = (c < IN_F) ? x[(size_t)(m0 + r) * IN_F + c] : 0.f;
            u16 h = f2bf(v);
            sA[0][r * 136 + c] = h;
            sA[1][r * 136 + c] = f2bf(v - bf2f(h));
        }
    } else {
        // wave w gathers node m0+w; lane holds 2 cols (1 dword of bf16 y row)
        int node = m0 + w;
        const u32* yd = (const u32*)yin;
        int col0 = lane * 2;
        float a0 = zin[(size_t)node * 128 + col0];
        float a1 = zin[(size_t)node * 128 + col0 + 1];
        {
            float d = dis[node];
            float sw = 2.f * d * d;
            u32 v = yd[(size_t)node * 64 + lane];
            a0 += sw * lo2f(v);
            a1 += sw * hi2f(v);
        }
        int s = offs[node], e = offs[node + 1];
        int p = s;
        int nUn = (e - s) & ~3;
        for (int q = 0; q < nUn; q += 4) {
            int c0 = ccol[p], c1 = ccol[p + 1], c2 = ccol[p + 2], c3 = ccol[p + 3];
            float w0 = cw[p], w1 = cw[p + 1], w2 = cw[p + 2], w3 = cw[p + 3];
            u32 v0 = yd[(size_t)c0 * 64 + lane];
            u32 v1 = yd[(size_t)c1 * 64 + lane];
            u32 v2 = yd[(size_t)c2 * 64 + lane];
            u32 v3 = yd[(size_t)c3 * 64 + lane];
            a0 += w0 * lo2f(v0) + w1 * lo2f(v1) + w2 * lo2f(v2) + w3 * lo2f(v3);
            a1 += w0 * hi2f(v0) + w1 * hi2f(v1) + w2 * hi2f(v2) + w3 * hi2f(v3);
            p += 4;
        }
        for (; p < e; ++p) {
            int c = ccol[p];
            float wt = cw[p];
            u32 v = yd[(size_t)c * 64 + lane];
            a0 += wt * lo2f(v);
            a1 += wt * hi2f(v);
        }
        // LayerNorm over 128 + ReLU
        float s1 = a0 + a1, s2 = a0 * a0 + a1 * a1;
#pragma unroll
        for (int m = 32; m >= 1; m >>= 1) {
            s1 += __shfl_xor(s1, m, 64);
            s2 += __shfl_xor(s2, m, 64);
        }
        float mu  = s1 * (1.0f / 128);
        float var = s2 * (1.0f / 128) - mu * mu;
        float inv = rsqrtf(var + 1e-5f);
        float o0 = fmaxf((a0 - mu) * inv, 0.f);
        float o1 = fmaxf((a1 - mu) * inv, 0.f);
        u16 h0 = f2bf(o0), h1 = f2bf(o1);
        sA[0][w * 136 + col0]     = h0;
        sA[0][w * 136 + col0 + 1] = h1;
        sA[1][w * 136 + col0]     = f2bf(o0 - bf2f(h0));
        sA[1][w * 136 + col0 + 1] = f2bf(o1 - bf2f(h1));
    }
    __syncthreads();

    // phase 2: wave w -> output tile w (tiles over [y|z] = 2*HOUT cols)
    constexpr int NTOT = HOUT / 8;
    if (w < NTOT) {
        int c16 = lane & 15, g = lane >> 4, koff = g * 8;
        const u16* pah = &sA[0][c16 * 136 + koff];
        const u16* pal = &sA[1][c16 * 136 + koff];
        const u16* pbh = Bh + (size_t)(w * 16 + c16) * 128 + koff;
        const u16* pbl = Bl + (size_t)(w * 16 + c16) * 128 + koff;
        f32x4 acc = (f32x4){0.f, 0.f, 0.f, 0.f};
#pragma unroll
        for (int kk = 0; kk < 128; kk += 32) {
            bf16x8 ah = *(const bf16x8*)(pah + kk);
            bf16x8 al = *(const bf16x8*)(pal + kk);
            bf16x8 bh = *(const bf16x8*)(pbh + kk);
            bf16x8 bl = *(const bf16x8*)(pbl + kk);
            acc = __builtin_amdgcn_mfma_f32_16x16x32_bf16(ah, bh, acc, 0, 0, 0);
            acc = __builtin_amdgcn_mfma_f32_16x16x32_bf16(al, bh, acc, 0, 0, 0);
            acc = __builtin_amdgcn_mfma_f32_16x16x32_bf16(ah, bl, acc, 0, 0, 0);
        }
        if (w < NTOT / 2) {                    // y half -> bf16
            int col = w * 16 + c16;
#pragma unroll
            for (int r = 0; r < 4; ++r)
                yout[(size_t)(m0 + g * 4 + r) * HOUT + col] = f2bf(acc[r]);
        } else {                               // z half -> f32
            int col = (w - NTOT / 2) * 16 + c16;
#pragma unroll
            for (int r = 0; r < 4; ++r)
                zout[(size_t)(m0 + g * 4 + r) * HOUT + col] = acc[r];
        }
    }
}

// ---------------------------------------------------------------------------
// Final: out = LN( gather(y3) + self + z3 ), H=48 padded, HREAL=47.
// Half-wave (32 lanes, 24 active dwords) per node.
// ---------------------------------------------------------------------------
__global__ __launch_bounds__(256) void final_ln_kernel(
    const u16* __restrict__ y, const float* __restrict__ z,
    const int* __restrict__ offs, const int* __restrict__ ccol,
    const float* __restrict__ cw, const float* __restrict__ dis,
    float* __restrict__ out, int N) {
    int gt = blockIdx.x * 256 + threadIdx.x;
    int node = gt >> 5;
    int hl = threadIdx.x & 31;
    if (node >= N) return;
    const bool act = hl < 24;
    const int col0 = hl * 2;
    const u32* yd = (const u32*)y;

    float a0 = 0.f, a1 = 0.f;
    if (act) {
        a0 = z[(size_t)node * 48 + col0];
        a1 = z[(size_t)node * 48 + col0 + 1];
    }
    {
        float d = dis[node];
        float sw = 2.f * d * d;
        u32 v = act ? yd[(size_t)node * 24 + hl] : 0u;
        a0 += sw * lo2f(v);
        a1 += sw * hi2f(v);
    }
    int s = offs[node], e = offs[node + 1];
    int p = s;
    int nUn = (e - s) & ~3;
    for (int q = 0; q < nUn; q += 4) {
        int c0 = ccol[p], c1 = ccol[p + 1], c2 = ccol[p + 2], c3 = ccol[p + 3];
        float w0 = cw[p], w1 = cw[p + 1], w2 = cw[p + 2], w3 = cw[p + 3];
        u32 v0 = 0u, v1 = 0u, v2 = 0u, v3 = 0u;
        if (act) {
            v0 = yd[(size_t)c0 * 24 + hl];
            v1 = yd[(size_t)c1 * 24 + hl];
            v2 = yd[(size_t)c2 * 24 + hl];
            v3 = yd[(size_t)c3 * 24 + hl];
        }
        a0 += w0 * lo2f(v0) + w1 * lo2f(v1) + w2 * lo2f(v2) + w3 * lo2f(v3);
        a1 += w0 * hi2f(v0) + w1 * hi2f(v1) + w2 * hi2f(v2) + w3 * hi2f(v3);
        p += 4;
    }
    for (; p < e; ++p) {
        int c = ccol[p];
        float wt = cw[p];
        u32 v = act ? yd[(size_t)c * 24 + hl] : 0u;
        a0 += wt * lo2f(v);
        a1 += wt * hi2f(v);
    }

    // LN over 47 real cols (col 47 is padding)
    float s1 = 0.f, s2 = 0.f;
    if (act) {
        bool ok1 = (col0 + 1 < OUT_F);
        s1 = a0 + (ok1 ? a1 : 0.f);
        s2 = a0 * a0 + (ok1 ? a1 * a1 : 0.f);
    }
#pragma unroll
    for (int m = 16; m >= 1; m >>= 1) {
        s1 += __shfl_xor(s1, m, 32);
        s2 += __shfl_xor(s2, m, 32);
    }
    float mu  = s1 * (1.0f / OUT_F);
    float var = s2 * (1.0f / OUT_F) - mu * mu;
    float inv = rsqrtf(var + 1e-5f);

    if (act) {
        out[(size_t)node * OUT_F + col0] = (a0 - mu) * inv;
        if (col0 + 1 < OUT_F)
            out[(size_t)node * OUT_F + col0 + 1] = (a1 - mu) * inv;
    }
}

// ---------------------------------------------------------------------------
extern "C" void kernel_launch(void* const* d_in, const int* in_sizes, int n_in,
                              void* d_out, int out_size, void* d_ws, size_t ws_size,
                              hipStream_t stream) {
    const float* x  = (const float*)d_in[0];
    const int*   ei = (const int*)d_in[1];
    const float* W1 = (const float*)d_in[2];
    const float* W2 = (const float*)d_in[3];
    const float* W3 = (const float*)d_in[4];
    float* out = (float*)d_out;

    const int N = in_sizes[0] / IN_F;   // 50000
    const int E = in_sizes[1] / 2;      // 800000
    const int* erow = ei;
    const int* ecol = ei + E;

    char* p = (char*)d_ws;
    auto alloc = [&](size_t bytes) -> void* {
        void* r = (void*)p;
        p += (bytes + 255) & ~(size_t)255;
        return r;
    };
    int*   cnt  = (int*)  alloc((size_t)N * 4);
    int*   offs = (int*)  alloc((size_t)(N + 1) * 4);
    int*   fill = (int*)  alloc((size_t)N * 4);
    float* dis  = (float*)alloc((size_t)N * 4);
    int*   bsum = (int*)  alloc((size_t)256 * 4);
    int*   ccol = (int*)  alloc((size_t)E * 4);
    float* cw   = (float*)alloc((size_t)E * 4);
    u16*   ya   = (u16*)  alloc((size_t)N * 128 * 2);
    float* za   = (float*)alloc((size_t)N * 128 * 4);
    u16*   yb   = (u16*)  alloc((size_t)N * 128 * 2);
    float* zb   = (float*)alloc((size_t)N * 128 * 4);
    u16*   B1h  = (u16*)  alloc((size_t)256 * 128 * 2);
    u16*   B1l  = (u16*)  alloc((size_t)256 * 128 * 2);
    u16*   B2h  = (u16*)  alloc((size_t)256 * 128 * 2);
    u16*   B2l  = (u16*)  alloc((size_t)256 * 128 * 2);
    u16*   B3h  = (u16*)  alloc((size_t)96 * 128 * 2);
    u16*   B3l  = (u16*)  alloc((size_t)96 * 128 * 2);

    hipMemsetAsync(cnt,  0, (size_t)N * 4, stream);
    hipMemsetAsync(fill, 0, (size_t)N * 4, stream);

    const int egrid = (E + 255) / 256;       // 3125
    const int nb    = (N + 255) / 256;       // 196

    count_kernel<<<egrid, 256, 0, stream>>>(erow, E, cnt);
    scan_bsum_kernel<<<nb, 256, 0, stream>>>(cnt, bsum, N);
    scan_mid_kernel<<<1, 256, 0, stream>>>(bsum, nb);
    scan_offs_kernel<<<nb, 256, 0, stream>>>(cnt, bsum, offs, dis, N, E);
    fill_kernel<<<egrid, 256, 0, stream>>>(erow, ecol, E, offs, fill, dis, ccol, cw);

    wtprep_all_kernel<<<608, 128, 0, stream>>>(W1, W2, W3, B1h, B1l, B2h, B2l, B3h, B3l);

    const int gblocks = N / 16;               // 3125

    // layer 1: x -> (y1,z1)
    fused_kernel<128, true><<<gblocks, 1024, 0, stream>>>(
        x, nullptr, nullptr, offs, ccol, cw, dis, B1h, B1l, ya, za, N);
    // layer 2: gather(y1)+z1 -> h1 -> (y2,z2)
    fused_kernel<128, false><<<gblocks, 1024, 0, stream>>>(
        nullptr, ya, za, offs, ccol, cw, dis, B2h, B2l, yb, zb, N);
    // layer 3: gather(y2)+z2 -> h2 -> (y3,z3)
    fused_kernel<48, false><<<gblocks, 1024, 0, stream>>>(
        nullptr, yb, zb, offs, ccol, cw, dis, B3h, B3l, ya, za, N);
    // final: out = LN(gather(y3)+self+z3)
    final_ln_kernel<<<(N * 32 + 255) / 256, 256, 0, stream>>>(
        ya, za, offs, ccol, cw, dis, out, N);
}

// Round 5
// 328.880 us; speedup vs baseline: 2.4869x; 1.0028x over previous
//
#include <hip/hip_runtime.h>

#define IN_F   100
#define HID_F  128
#define OUT_F  47

typedef short bf16x8 __attribute__((ext_vector_type(8)));
typedef float f32x4  __attribute__((ext_vector_type(4)));
typedef unsigned short u16;
typedef unsigned int   u32;

__device__ __forceinline__ u16 f2bf(float f) {
    u32 u = __float_as_uint(f);
    u += 0x7FFFu + ((u >> 16) & 1u);           // RNE
    return (u16)(u >> 16);
}
__device__ __forceinline__ float bf2f(u16 b) { return __uint_as_float(((u32)b) << 16); }
__device__ __forceinline__ float lo2f(u32 v) { return __uint_as_float(v << 16); }
__device__ __forceinline__ float hi2f(u32 v) { return __uint_as_float(v & 0xFFFF0000u); }

// ---------------------------------------------------------------------------
// CSR build
// ---------------------------------------------------------------------------
__global__ void count_kernel(const int* __restrict__ row, int E, int* __restrict__ cnt) {
    int e = blockIdx.x * blockDim.x + threadIdx.x;
    if (e < E) atomicAdd(&cnt[row[e]], 1);
}

__global__ void scan_bsum_kernel(const int* __restrict__ cnt, int* __restrict__ bsum, int N) {
    __shared__ int red[4];
    int i = blockIdx.x * 256 + threadIdx.x;
    int v = (i < N) ? cnt[i] : 0;
#pragma unroll
    for (int m = 32; m >= 1; m >>= 1) v += __shfl_xor(v, m, 64);
    if ((threadIdx.x & 63) == 0) red[threadIdx.x >> 6] = v;
    __syncthreads();
    if (threadIdx.x == 0) bsum[blockIdx.x] = red[0] + red[1] + red[2] + red[3];
}

__global__ void scan_mid_kernel(int* __restrict__ bsum, int nb) {
    __shared__ int s[256];
    int t = threadIdx.x;
    int v = (t < nb) ? bsum[t] : 0;
    s[t] = v;
    __syncthreads();
    for (int o = 1; o < 256; o <<= 1) {
        int u = (t >= o) ? s[t - o] : 0;
        __syncthreads();
        s[t] += u;
        __syncthreads();
    }
    if (t < nb) bsum[t] = s[t] - v;     // exclusive
}

__global__ void scan_offs_kernel(const int* __restrict__ cnt, const int* __restrict__ bsum,
                                 int* __restrict__ offs, float* __restrict__ dis, int N, int E) {
    __shared__ int s[256];
    int b = blockIdx.x, t = threadIdx.x;
    int i = b * 256 + t;
    int v = (i < N) ? cnt[i] : 0;
    s[t] = v;
    __syncthreads();
    for (int o = 1; o < 256; o <<= 1) {
        int u = (t >= o) ? s[t - o] : 0;
        __syncthreads();
        s[t] += u;
        __syncthreads();
    }
    if (i < N) {
        offs[i] = bsum[b] + s[t] - v;
        dis[i]  = rsqrtf((float)v + 1.0f);   // +1 self loop
    }
    if (b == 0 && t == 0) offs[N] = E;
}

__global__ void fill_kernel(const int* __restrict__ row, const int* __restrict__ col, int E,
                            const int* __restrict__ offs, int* __restrict__ fill,
                            const float* __restrict__ dis,
                            int* __restrict__ ccol, float* __restrict__ cw) {
    int e = blockIdx.x * blockDim.x + threadIdx.x;
    if (e < E) {
        int r = row[e], c = col[e];
        int pos = offs[r] + atomicAdd(&fill[r], 1);
        ccol[pos] = c;
        cw[pos]   = dis[r] * dis[c];
    }
}

// ---------------------------------------------------------------------------
// All three weight preps in one launch.  B_l = [ Wa^T ; Wx^T ] as [2*NPAD][128] hi/lo.
// ---------------------------------------------------------------------------
__global__ void wtprep_all_kernel(const float* __restrict__ W1, const float* __restrict__ W2,
                                  const float* __restrict__ W3,
                                  u16* __restrict__ B1h, u16* __restrict__ B1l,
                                  u16* __restrict__ B2h, u16* __restrict__ B2l,
                                  u16* __restrict__ B3h, u16* __restrict__ B3l) {
    int b = blockIdx.x, k = threadIdx.x;   // k: 0..127
    const float* W; u16 *Bh, *Bl; int KSRC, NSRC, NPAD, n;
    if (b < 256)      { W = W1; Bh = B1h; Bl = B1l; KSRC = IN_F;  NSRC = HID_F; NPAD = 128; n = b; }
    else if (b < 512) { W = W2; Bh = B2h; Bl = B2l; KSRC = HID_F; NSRC = HID_F; NPAD = 128; n = b - 256; }
    else              { W = W3; Bh = B3h; Bl = B3l; KSRC = HID_F; NSRC = OUT_F; NPAD = 48;  n = b - 512; }
    int half = (n >= NPAD) ? 1 : 0;
    int cc = n - half * NPAD;
    float v = (cc < NSRC && k < KSRC) ? W[(size_t)(half * KSRC + k) * NSRC + cc] : 0.f;
    u16 h = f2bf(v);
    Bh[(size_t)n * 128 + k] = h;
    Bl[(size_t)n * 128 + k] = f2bf(v - bf2f(h));
}

// ---------------------------------------------------------------------------
// Fused per-16-node-tile kernel.
// Gather phase (!FIRST): wave w = node m0+w.  lane = (eg,seg): eg = lane>>4
// selects 1 of 4 concurrent edges, seg = lane&15 selects the 16-B segment of
// the 256-B bf16 y row.  Partials butterfly-reduced over eg, LN over seg,
// normalized hi/lo row written to LDS.
// GEMM phase: wave w computes 16x16 output tile w of [y|z] = A @ B^T.
// C/D frag: col = lane&15, row = (lane>>4)*4 + reg.
// ---------------------------------------------------------------------------
template <int HOUT, int YSTR, bool FIRST>
__global__ __launch_bounds__(1024) void fused_kernel(
    const float* __restrict__ x,
    const u16* __restrict__ yin, const float* __restrict__ zin,
    const int* __restrict__ offs, const int* __restrict__ ccol,
    const float* __restrict__ cw, const float* __restrict__ dis,
    const u16* __restrict__ Bh, const u16* __restrict__ Bl,
    u16* __restrict__ yout, float* __restrict__ zout, int N) {
    constexpr int STR = 152;            // u16 stride: 304 B -> 12 dw mod 32 -> <=2-way
    __shared__ u16 sA[2][16 * STR];
    int tid = threadIdx.x;
    int m0 = blockIdx.x * 16;
    int w = tid >> 6, lane = tid & 63;

    if (FIRST) {
#pragma unroll
        for (int idx = tid; idx < 16 * 128; idx += 1024) {
            int r = idx >> 7, c = idx & 127;
            float v = (c < IN_F) ? x[(size_t)(m0 + r) * IN_F + c] : 0.f;
            u16 h = f2bf(v);
            sA[0][r * STR + c] = h;
            sA[1][r * STR + c] = f2bf(v - bf2f(h));
        }
    } else {
        int node = m0 + w;
        int seg = lane & 15, eg = lane >> 4;
        float a[8];
        if (eg == 0) {     // z + diag-enhanced self loop
            float d = dis[node];
            float sw = 2.f * d * d;
            int4   sv = *(const int4*)  (yin + (size_t)node * 128 + seg * 8);
            float4 z0 = *(const float4*)(zin + (size_t)node * 128 + seg * 8);
            float4 z1 = *(const float4*)(zin + (size_t)node * 128 + seg * 8 + 4);
            a[0] = z0.x + sw * lo2f(sv.x); a[1] = z0.y + sw * hi2f(sv.x);
            a[2] = z0.z + sw * lo2f(sv.y); a[3] = z0.w + sw * hi2f(sv.y);
            a[4] = z1.x + sw * lo2f(sv.z); a[5] = z1.y + sw * hi2f(sv.z);
            a[6] = z1.z + sw * lo2f(sv.w); a[7] = z1.w + sw * hi2f(sv.w);
        } else {
#pragma unroll
            for (int j = 0; j < 8; ++j) a[j] = 0.f;
        }

        int s = offs[node], e = offs[node + 1];
#pragma unroll 2
        for (int p0 = s; p0 < e; p0 += 4) {
            int idx = p0 + eg;
            int idc = min(idx, e - 1);
            int c   = ccol[idc];
            float wt = (idx < e) ? cw[idc] : 0.f;
            int4 v = *(const int4*)(yin + (size_t)c * 128 + seg * 8);
            a[0] += wt * lo2f(v.x); a[1] += wt * hi2f(v.x);
            a[2] += wt * lo2f(v.y); a[3] += wt * hi2f(v.y);
            a[4] += wt * lo2f(v.z); a[5] += wt * hi2f(v.z);
            a[6] += wt * lo2f(v.w); a[7] += wt * hi2f(v.w);
        }

        // reduce the 4 edge-groups
#pragma unroll
        for (int j = 0; j < 8; ++j) {
            a[j] += __shfl_xor(a[j], 16, 64);
            a[j] += __shfl_xor(a[j], 32, 64);
        }
        // LN stats over 128 cols (reduce across 16 segments)
        float s1 = 0.f, s2 = 0.f;
#pragma unroll
        for (int j = 0; j < 8; ++j) { s1 += a[j]; s2 += a[j] * a[j]; }
#pragma unroll
        for (int m = 8; m >= 1; m >>= 1) {
            s1 += __shfl_xor(s1, m, 64);
            s2 += __shfl_xor(s2, m, 64);
        }
        float mu  = s1 * (1.0f / 128);
        float var = s2 * (1.0f / 128) - mu * mu;
        float inv = rsqrtf(var + 1e-5f);
        if (eg == 0) {
            bf16x8 hv, lv;
#pragma unroll
            for (int j = 0; j < 8; ++j) {
                float o = fmaxf((a[j] - mu) * inv, 0.f);
                u16 h = f2bf(o);
                hv[j] = (short)h;
                lv[j] = (short)f2bf(o - bf2f(h));
            }
            *(bf16x8*)(&sA[0][w * STR + seg * 8]) = hv;
            *(bf16x8*)(&sA[1][w * STR + seg * 8]) = lv;
        }
    }
    __syncthreads();

    // GEMM phase: wave w -> output tile w over [y|z] (2*HOUT cols)
    constexpr int NTOT = HOUT / 8;
    if (w < NTOT) {
        int c16 = lane & 15, g = lane >> 4, koff = g * 8;
        const u16* pah = &sA[0][c16 * STR + koff];
        const u16* pal = &sA[1][c16 * STR + koff];
        const u16* pbh = Bh + (size_t)(w * 16 + c16) * 128 + koff;
        const u16* pbl = Bl + (size_t)(w * 16 + c16) * 128 + koff;
        f32x4 acc = (f32x4){0.f, 0.f, 0.f, 0.f};
#pragma unroll
        for (int kk = 0; kk < 128; kk += 32) {
            bf16x8 ah = *(const bf16x8*)(pah + kk);
            bf16x8 al = *(const bf16x8*)(pal + kk);
            bf16x8 bh = *(const bf16x8*)(pbh + kk);
            bf16x8 bl = *(const bf16x8*)(pbl + kk);
            acc = __builtin_amdgcn_mfma_f32_16x16x32_bf16(ah, bh, acc, 0, 0, 0);
            acc = __builtin_amdgcn_mfma_f32_16x16x32_bf16(al, bh, acc, 0, 0, 0);
            acc = __builtin_amdgcn_mfma_f32_16x16x32_bf16(ah, bl, acc, 0, 0, 0);
        }
        if (w < NTOT / 2) {                    // y half -> bf16 (stride YSTR)
            int col = w * 16 + c16;
#pragma unroll
            for (int r = 0; r < 4; ++r)
                yout[(size_t)(m0 + g * 4 + r) * YSTR + col] = f2bf(acc[r]);
        } else {                               // z half -> f32 (stride HOUT)
            int col = (w - NTOT / 2) * 16 + c16;
#pragma unroll
            for (int r = 0; r < 4; ++r)
                zout[(size_t)(m0 + g * 4 + r) * HOUT + col] = acc[r];
        }
    }
    if constexpr (HOUT == 48) {
        // zero the y pad cols [48,64) with an otherwise-idle wave
        if (w == NTOT) {
#pragma unroll
            for (int k = 0; k < 2; ++k) {
                int ii = lane * 2 + k;          // 0..127
                int r = ii >> 3, cc = ii & 7;   // 16 rows x 8 u32
                ((u32*)(yout + (size_t)(m0 + r) * YSTR + 48))[cc] = 0u;
            }
        }
    }
}

// ---------------------------------------------------------------------------
// Final: out = LN( gather(y3) + self + z3 ).  y3 padded [N][64] bf16 (128 B),
// z3 [N][48] f32.  Wave per node; eg = lane>>3 (8 edges/iter), seg = lane&7.
// ---------------------------------------------------------------------------
__global__ __launch_bounds__(256) void final_ln_kernel(
    const u16* __restrict__ y, const float* __restrict__ z,
    const int* __restrict__ offs, const int* __restrict__ ccol,
    const float* __restrict__ cw, const float* __restrict__ dis,
    float* __restrict__ out, int N) {
    int node = (blockIdx.x * 256 + threadIdx.x) >> 6;
    int lane = threadIdx.x & 63;
    if (node >= N) return;
    int seg = lane & 7, eg = lane >> 3;

    float a[8];
    if (eg == 0) {
        float d = dis[node];
        float sw = 2.f * d * d;
        int4 sv = *(const int4*)(y + (size_t)node * 64 + seg * 8);
        float4 z0 = {0.f, 0.f, 0.f, 0.f}, z1 = {0.f, 0.f, 0.f, 0.f};
        if (seg < 6) {
            z0 = *(const float4*)(z + (size_t)node * 48 + seg * 8);
            z1 = *(const float4*)(z + (size_t)node * 48 + seg * 8 + 4);
        }
        a[0] = z0.x + sw * lo2f(sv.x); a[1] = z0.y + sw * hi2f(sv.x);
        a[2] = z0.z + sw * lo2f(sv.y); a[3] = z0.w + sw * hi2f(sv.y);
        a[4] = z1.x + sw * lo2f(sv.z); a[5] = z1.y + sw * hi2f(sv.z);
        a[6] = z1.z + sw * lo2f(sv.w); a[7] = z1.w + sw * hi2f(sv.w);
    } else {
#pragma unroll
        for (int j = 0; j < 8; ++j) a[j] = 0.f;
    }

    int s = offs[node], e = offs[node + 1];
#pragma unroll 2
    for (int p0 = s; p0 < e; p0 += 8) {
        int idx = p0 + eg;
        int idc = min(idx, e - 1);
        int c   = ccol[idc];
        float wt = (idx < e) ? cw[idc] : 0.f;
        int4 v = *(const int4*)(y + (size_t)c * 64 + seg * 8);
        a[0] += wt * lo2f(v.x); a[1] += wt * hi2f(v.x);
        a[2] += wt * lo2f(v.y); a[3] += wt * hi2f(v.y);
        a[4] += wt * lo2f(v.z); a[5] += wt * hi2f(v.z);
        a[6] += wt * lo2f(v.w); a[7] += wt * hi2f(v.w);
    }

#pragma unroll
    for (int j = 0; j < 8; ++j) {
        a[j] += __shfl_xor(a[j], 8, 64);
        a[j] += __shfl_xor(a[j], 16, 64);
        a[j] += __shfl_xor(a[j], 32, 64);
    }
    // LN over the 47 real cols
    float s1 = 0.f, s2 = 0.f;
#pragma unroll
    for (int j = 0; j < 8; ++j) {
        int col = seg * 8 + j;
        if (col < OUT_F) { s1 += a[j]; s2 += a[j] * a[j]; }
    }
#pragma unroll
    for (int m = 4; m >= 1; m >>= 1) {
        s1 += __shfl_xor(s1, m, 64);
        s2 += __shfl_xor(s2, m, 64);
    }
    float mu  = s1 * (1.0f / OUT_F);
    float var = s2 * (1.0f / OUT_F) - mu * mu;
    float inv = rsqrtf(var + 1e-5f);

    if (eg == 0) {
#pragma unroll
        for (int j = 0; j < 8; ++j) {
            int col = seg * 8 + j;
            if (col < OUT_F)
                out[(size_t)node * OUT_F + col] = (a[j] - mu) * inv;
        }
    }
}

// ---------------------------------------------------------------------------
extern "C" void kernel_launch(void* const* d_in, const int* in_sizes, int n_in,
                              void* d_out, int out_size, void* d_ws, size_t ws_size,
                              hipStream_t stream) {
    const float* x  = (const float*)d_in[0];
    const int*   ei = (const int*)d_in[1];
    const float* W1 = (const float*)d_in[2];
    const float* W2 = (const float*)d_in[3];
    const float* W3 = (const float*)d_in[4];
    float* out = (float*)d_out;

    const int N = in_sizes[0] / IN_F;   // 50000
    const int E = in_sizes[1] / 2;      // 800000
    const int* erow = ei;
    const int* ecol = ei + E;

    char* p = (char*)d_ws;
    auto alloc = [&](size_t bytes) -> void* {
        void* r = (void*)p;
        p += (bytes + 255) & ~(size_t)255;
        return r;
    };
    int*   cnt  = (int*)  alloc((size_t)N * 4);
    int*   offs = (int*)  alloc((size_t)(N + 1) * 4);
    int*   fill = (int*)  alloc((size_t)N * 4);
    float* dis  = (float*)alloc((size_t)N * 4);
    int*   bsum = (int*)  alloc((size_t)256 * 4);
    int*   ccol = (int*)  alloc((size_t)(E + 16) * 4);
    float* cw   = (float*)alloc((size_t)(E + 16) * 4);
    u16*   ya   = (u16*)  alloc((size_t)N * 128 * 2);
    float* za   = (float*)alloc((size_t)N * 128 * 4);
    u16*   yb   = (u16*)  alloc((size_t)N * 128 * 2);
    float* zb   = (float*)alloc((size_t)N * 128 * 4);
    u16*   B1h  = (u16*)  alloc((size_t)256 * 128 * 2);
    u16*   B1l  = (u16*)  alloc((size_t)256 * 128 * 2);
    u16*   B2h  = (u16*)  alloc((size_t)256 * 128 * 2);
    u16*   B2l  = (u16*)  alloc((size_t)256 * 128 * 2);
    u16*   B3h  = (u16*)  alloc((size_t)96 * 128 * 2);
    u16*   B3l  = (u16*)  alloc((size_t)96 * 128 * 2);

    hipMemsetAsync(cnt,  0, (size_t)N * 4, stream);
    hipMemsetAsync(fill, 0, (size_t)N * 4, stream);

    const int egrid = (E + 255) / 256;       // 3125
    const int nb    = (N + 255) / 256;       // 196

    count_kernel<<<egrid, 256, 0, stream>>>(erow, E, cnt);
    scan_bsum_kernel<<<nb, 256, 0, stream>>>(cnt, bsum, N);
    scan_mid_kernel<<<1, 256, 0, stream>>>(bsum, nb);
    scan_offs_kernel<<<nb, 256, 0, stream>>>(cnt, bsum, offs, dis, N, E);
    fill_kernel<<<egrid, 256, 0, stream>>>(erow, ecol, E, offs, fill, dis, ccol, cw);

    wtprep_all_kernel<<<608, 128, 0, stream>>>(W1, W2, W3, B1h, B1l, B2h, B2l, B3h, B3l);

    const int gblocks = N / 16;               // 3125

    // layer 1: x -> (y1,z1)
    fused_kernel<128, 128, true><<<gblocks, 1024, 0, stream>>>(
        x, nullptr, nullptr, offs, ccol, cw, dis, B1h, B1l, ya, za, N);
    // layer 2: gather(y1)+z1 -> h1 -> (y2,z2)
    fused_kernel<128, 128, false><<<gblocks, 1024, 0, stream>>>(
        nullptr, ya, za, offs, ccol, cw, dis, B2h, B2l, yb, zb, N);
    // layer 3: gather(y2)+z2 -> h2 -> (y3,z3)   y3 padded to stride 64
    fused_kernel<48, 64, false><<<gblocks, 1024, 0, stream>>>(
        nullptr, yb, zb, offs, ccol, cw, dis, B3h, B3l, ya, za, N);
    // final: out = LN(gather(y3)+self+z3)
    final_ln_kernel<<<(N * 64 + 255) / 256, 256, 0, stream>>>(
        ya, za, offs, ccol, cw, dis, out, N);
}